// Round 4
// baseline (91.332 us; speedup 1.0000x reference)
//
#include <hip/hip_runtime.h>
#include <math.h>

#define TS 64
#define NTHREADS 256
#define JPT 16                      // j's per thread (4 quads)

// ---- u = diff^2 LUT: float-bit indexed, 24 octaves [2^-16, 2^8), 32 segs each
#define LUTN 768
#define OCT_LO (-16)                // u_min = 2^-16  -> d_min = 2^-8
#define U_MIN 1.52587890625e-5f     // 2^-16
#define U_MAX 255.999f              // just under 2^8
// (bits >> 15) for u = 2^-16: exponent field (127-16)=111 -> 111<<8
#define IDX_BIAS 28416u
#define FRAC_SCALE 3.814697265625e-6f   // 2^-18

typedef float v2f __attribute__((ext_vector_type(2)));

__device__ __forceinline__ float fsqrt(float x) {
#if __has_builtin(__builtin_amdgcn_sqrtf)
    return __builtin_amdgcn_sqrtf(x);
#else
    return sqrtf(x);
#endif
}
__device__ __forceinline__ float fmed3(float x, float lo, float hi) {
#if __has_builtin(__builtin_amdgcn_fmed3f)
    return __builtin_amdgcn_fmed3f(x, lo, hi);
#else
    return fminf(fmaxf(x, lo), hi);
#endif
}

// f(d) = sum of 4 sigmoids sigma(thr - d); LUT-build only (exact path)
__device__ __forceinline__ float sig4(float d) {
    const float e = expf(d);
    return 1.0f / (1.0f + e * 0.60653065971263342360f)   // exp(-0.5)
         + 1.0f / (1.0f + e * 0.36787944117144232160f)   // exp(-1)
         + 1.0f / (1.0f + e * 0.13533528323661269189f)   // exp(-2)
         + 1.0f / (1.0f + e * 0.01831563888873418029f);  // exp(-4)
}

__device__ __forceinline__ void pair_tail(float sqp, float sqt, float cut2,
                                          const char* __restrict__ lutB,
                                          float& num, float& den) {
    // diff^2 = sqt + sqp - 2*sqrt(sqt*sqp): ONE sqrt per pair
    const float r  = fsqrt(sqt * sqp);
    const float u0 = fmaf(-2.0f, r, sqt + sqp);
    const float u  = fmed3(u0, U_MIN, U_MAX);
    const unsigned int bits = __float_as_uint(u);
    const float2 L = *(const float2*)(lutB + ((bits >> 15) & ~7u)); // {f0, f1-f0}
    const float fr = (float)(bits & 0x3FFFFu) * FRAC_SCALE;
    const float s  = fmaf(fr, L.y, L.x);
    const float m  = (sqt < cut2) ? 1.0f : 0.0f;   // cut2=0 when !cm_j kills pair
    num = fmaf(m, s, num);
    den += m;
}

__global__ __launch_bounds__(NTHREADS) void lddt_tile_kernel(
    const float* __restrict__ pred, const float* __restrict__ tru,
    const int* __restrict__ is_dna, const int* __restrict__ is_rna,
    const int* __restrict__ cmask,
    float* __restrict__ pnum, float* __restrict__ pden,
    int n, int T, int nslots)
{
    __shared__ __align__(16) float sPX[TS], sPY[TS], sPZ[TS];
    __shared__ __align__(16) float sTX[TS], sTY[TS], sTZ[TS];
    __shared__ __align__(16) float sCut[2 * TS];   // squared cutoffs [nt_i | other]
    __shared__ float2 sLUT[LUTN];
    __shared__ float wnum[4], wden[4];

    const int tid = threadIdx.x;

    // ---- decode block -> (bi, ti, tj) over upper-triangular tiles ----
    int slot = blockIdx.x;
    const int bi = slot / nslots;
    slot -= bi * nslots;
    const int W = 2 * T + 1;
    int ti = (int)(((float)W - fsqrt((float)(W * W - 8 * slot))) * 0.5f);
    while ((ti + 1) * (W - (ti + 1)) / 2 <= slot) ++ti;   // fixup fp rounding
    while (ti * (W - ti) / 2 > slot) --ti;
    const int tj = ti + (slot - ti * (W - ti) / 2);
    const bool diag = (ti == tj);
    const int i0 = ti * TS, j0 = tj * TS;
    const size_t base = (size_t)bi * n;

    // ---- stage j-tile (SoA) + per-j SQUARED cutoffs (cm_j & nt_j folded) ----
    if (tid < TS) {
        const int j = j0 + tid;
        const float* p = pred + (base + j) * 3;
        const float* q = tru  + (base + j) * 3;
        sPX[tid] = p[0]; sPY[tid] = p[1]; sPZ[tid] = p[2];
        sTX[tid] = q[0]; sTY[tid] = q[1]; sTZ[tid] = q[2];
        const bool ntj = (is_dna[base + j] != 0) || (is_rna[base + j] != 0);
        const bool cmj = (cmask[base + j] != 0);
        sCut[tid]      = cmj ? (ntj ? 900.0f : 225.0f) : 0.0f;
        sCut[TS + tid] = cmj ? 225.0f : 0.0f;
    }

    // ---- build u->f LUT: octave oct (u in [2^(oct-16), 2^(oct-15))), 32 segs ----
    for (int e = tid; e < LUTN; e += NTHREADS) {
        const int oct = e >> 5;                 // 0..23
        const int k   = e & 31;
        const float base2 = exp2f((float)(oct + OCT_LO));
        const float u0 = base2 * (1.0f + (float)k * 0.03125f);
        const float u1 = u0 + base2 * 0.03125f;
        const float f0 = sig4(fsqrt(u0));
        const float f1 = sig4(fsqrt(u1));
        sLUT[e] = make_float2(f0, f1 - f0);
    }

    // ---- per-thread row data: 4 waves x 64 rows; wave w covers 16 j's ----
    const int il = tid & (TS - 1);
    const int i  = i0 + il;
    const float* p = pred + (base + i) * 3;
    const float* q = tru  + (base + i) * 3;
    const float pix = p[0], piy = p[1], piz = p[2];
    const float tix = q[0], tiy = q[1], tiz = q[2];
    const bool nti = (is_dna[base + i] != 0) || (is_rna[base + i] != 0);
    const float cmf = (cmask[base + i] != 0) ? 1.0f : 0.0f;
    __syncthreads();

    const float* cutsel = nti ? &sCut[0] : &sCut[TS];
    const char* lutB = (const char*)sLUT - IDX_BIAS;   // bias folded into base
    const int kbase = (tid >> 6) * JPT;   // wave-uniform -> LDS broadcast reads

    float num = 0.0f, den = 0.0f;
    const v2f px2 = {pix, pix}, py2 = {piy, piy}, pz2 = {piz, piz};
    const v2f tx2 = {tix, tix}, ty2 = {tiy, tiy}, tz2 = {tiz, tiz};

    #pragma unroll
    for (int qd = 0; qd < JPT / 4; ++qd) {
        const int jq = kbase + 4 * qd;
        const float4 PX = *(const float4*)&sPX[jq];
        const float4 PY = *(const float4*)&sPY[jq];
        const float4 PZ = *(const float4*)&sPZ[jq];
        const float4 TX = *(const float4*)&sTX[jq];
        const float4 TY = *(const float4*)&sTY[jq];
        const float4 TZ = *(const float4*)&sTZ[jq];
        const float4 CT = *(const float4*)&cutsel[jq];

        // duo A = (j, j+1), duo B = (j+2, j+3): packed f32 distance math
        v2f dx, dy, dz, sqpA, sqpB, sqtA, sqtB;

        dx = px2 - (v2f){PX.x, PX.y}; dy = py2 - (v2f){PY.x, PY.y}; dz = pz2 - (v2f){PZ.x, PZ.y};
        sqpA = dx * dx + dy * dy + dz * dz;
        dx = tx2 - (v2f){TX.x, TX.y}; dy = ty2 - (v2f){TY.x, TY.y}; dz = tz2 - (v2f){TZ.x, TZ.y};
        sqtA = dx * dx + dy * dy + dz * dz;

        dx = px2 - (v2f){PX.z, PX.w}; dy = py2 - (v2f){PY.z, PY.w}; dz = pz2 - (v2f){PZ.z, PZ.w};
        sqpB = dx * dx + dy * dy + dz * dz;
        dx = tx2 - (v2f){TX.z, TX.w}; dy = ty2 - (v2f){TY.z, TY.w}; dz = tz2 - (v2f){TZ.z, TZ.w};
        sqtB = dx * dx + dy * dy + dz * dz;

        pair_tail(sqpA.x, sqtA.x, CT.x, lutB, num, den);
        pair_tail(sqpA.y, sqtA.y, CT.y, lutB, num, den);
        pair_tail(sqpB.x, sqtB.x, CT.z, lutB, num, den);
        pair_tail(sqpB.y, sqtB.y, CT.w, lutB, num, den);
    }

    // fold row cm_i; remove self-pair contribution on diagonal tiles.
    // self pair: u=0 -> clamped to U_MIN -> LUT entry 0, frac 0 -> sig4(2^-8)
    num *= cmf;
    den *= cmf;
    if (diag && tid < TS) {   // exactly once per row i
        num -= cmf * sig4(0.00390625f);
        den -= cmf;
    }

    // ---- wave (64) then block reduction ----
    #pragma unroll
    for (int off = 32; off > 0; off >>= 1) {
        num += __shfl_down(num, off, 64);
        den += __shfl_down(den, off, 64);
    }
    const int w = tid >> 6;
    if ((tid & 63) == 0) { wnum[w] = num; wden[w] = den; }
    __syncthreads();

    if (tid == 0) {
        const float tn = wnum[0] + wnum[1] + wnum[2] + wnum[3];
        const float td = wden[0] + wden[1] + wden[2] + wden[3];
        pnum[blockIdx.x] = diag ? tn : tn * 2.0f;   // off-diagonal tiles count twice
        pden[blockIdx.x] = diag ? td : td * 2.0f;
    }
}

__global__ __launch_bounds__(256) void lddt_final_kernel(
    const float* __restrict__ pnum, const float* __restrict__ pden,
    float* __restrict__ out, int nslots)
{
    __shared__ double sn0[4], sn1[4], sd0[4], sd1[4];
    double n0 = 0, n1 = 0, d0 = 0, d1 = 0;
    for (int s = threadIdx.x; s < 2 * nslots; s += 256) {
        if (s < nslots) { n0 += (double)pnum[s]; d0 += (double)pden[s]; }
        else            { n1 += (double)pnum[s]; d1 += (double)pden[s]; }
    }
    #pragma unroll
    for (int off = 32; off > 0; off >>= 1) {
        n0 += __shfl_down(n0, off, 64); d0 += __shfl_down(d0, off, 64);
        n1 += __shfl_down(n1, off, 64); d1 += __shfl_down(d1, off, 64);
    }
    const int w = threadIdx.x >> 6;
    if ((threadIdx.x & 63) == 0) { sn0[w] = n0; sn1[w] = n1; sd0[w] = d0; sd1[w] = d1; }
    __syncthreads();
    if (threadIdx.x == 0) {
        double N0 = sn0[0] + sn0[1] + sn0[2] + sn0[3];
        double N1 = sn1[0] + sn1[1] + sn1[2] + sn1[3];
        double D0 = sd0[0] + sd0[1] + sd0[2] + sd0[3];
        double D1 = sd1[0] + sd1[1] + sd1[2] + sd1[3];
        D0 = D0 > 1.0 ? D0 : 1.0;
        D1 = D1 > 1.0 ? D1 : 1.0;
        const double l0 = 0.25 * N0 / D0;   // 0.25 = mean over 4 thresholds
        const double l1 = 0.25 * N1 / D1;
        out[0] = (float)(1.0 - 0.5 * (l0 + l1));
    }
}

extern "C" void kernel_launch(void* const* d_in, const int* in_sizes, int n_in,
                              void* d_out, int out_size, void* d_ws, size_t ws_size,
                              hipStream_t stream) {
    const float* pred = (const float*)d_in[0];
    const float* tru  = (const float*)d_in[1];
    const int*   dna  = (const int*)d_in[2];
    const int*   rna  = (const int*)d_in[3];
    const int*   cm   = (const int*)d_in[4];
    float* out = (float*)d_out;

    const int B = 2;
    const int n = in_sizes[2] / B;        // is_dna has b*n elements
    const int T = n / TS;                 // 64 tiles per row
    const int nslots = T * (T + 1) / 2;   // 2080 per batch

    float* pnum = (float*)d_ws;
    float* pden = (float*)((char*)d_ws + (size_t)B * nslots * sizeof(float));

    const int grid = B * nslots;          // triangular launch: no dead blocks

    hipLaunchKernelGGL(lddt_tile_kernel, dim3(grid), dim3(NTHREADS), 0, stream,
                       pred, tru, dna, rna, cm, pnum, pden, n, T, nslots);
    hipLaunchKernelGGL(lddt_final_kernel, dim3(1), dim3(256), 0, stream,
                       pnum, pden, out, nslots);
}

// Round 5
// 83.709 us; speedup vs baseline: 1.0911x; 1.0911x over previous
//
#include <hip/hip_runtime.h>
#include <math.h>

#define TS 64
#define NTHREADS 256
#define JPT 16                      // j's per thread (4 quads)

// ---- u = diff^2 LUT: float-bit indexed, 24 octaves [2^-16, 2^8), 32 segs each
#define LUTN 768
#define OCT_LO (-16)                // u_min = 2^-16  -> d_min = 2^-8
#define U_MIN 1.52587890625e-5f     // 2^-16
#define U_MAX 255.999f              // just under 2^8
// (bits >> 15) for u = 2^-16: exponent field (127-16)=111 -> 111<<8
#define IDX_BIAS 28416u
#define FRAC_SCALE 3.814697265625e-6f   // 2^-18

typedef float v2f __attribute__((ext_vector_type(2)));

__device__ __forceinline__ float fsqrt(float x) {
#if __has_builtin(__builtin_amdgcn_sqrtf)
    return __builtin_amdgcn_sqrtf(x);
#else
    return sqrtf(x);
#endif
}
__device__ __forceinline__ float fmed3(float x, float lo, float hi) {
#if __has_builtin(__builtin_amdgcn_fmed3f)
    return __builtin_amdgcn_fmed3f(x, lo, hi);
#else
    return fminf(fmaxf(x, lo), hi);
#endif
}

// f(d) = sum of 4 sigmoids sigma(thr - d); LUT-build kernel only (exact path)
__device__ __forceinline__ float sig4(float d) {
    const float e = expf(d);
    return 1.0f / (1.0f + e * 0.60653065971263342360f)   // exp(-0.5)
         + 1.0f / (1.0f + e * 0.36787944117144232160f)   // exp(-1)
         + 1.0f / (1.0f + e * 0.13533528323661269189f)   // exp(-2)
         + 1.0f / (1.0f + e * 0.01831563888873418029f);  // exp(-4)
}

// ---- one-time LUT build: 768 entries of {f0, f1-f0} ----
__global__ __launch_bounds__(256) void lut_build_kernel(float2* __restrict__ gLUT) {
    const int e = blockIdx.x * 256 + threadIdx.x;
    if (e < LUTN) {
        const int oct = e >> 5;                 // 0..23
        const int k   = e & 31;
        const float base2 = exp2f((float)(oct + OCT_LO));
        const float u0 = base2 * (1.0f + (float)k * 0.03125f);
        const float u1 = u0 + base2 * 0.03125f;
        const float f0 = sig4(fsqrt(u0));
        const float f1 = sig4(fsqrt(u1));
        gLUT[e] = make_float2(f0, f1 - f0);
    }
}

__device__ __forceinline__ void pair_tail(float sqp, float sqt, float cut2,
                                          const char* __restrict__ lutB,
                                          float& num, float& den) {
    // diff^2 = sqt + sqp - 2*sqrt(sqt*sqp): ONE sqrt per pair
    const float r  = fsqrt(sqt * sqp);
    const float u0 = fmaf(-2.0f, r, sqt + sqp);
    const float u  = fmed3(u0, U_MIN, U_MAX);
    const unsigned int bits = __float_as_uint(u);
    const float2 L = *(const float2*)(lutB + ((bits >> 15) & ~7u)); // {f0, f1-f0}
    const float fr = (float)(bits & 0x3FFFFu) * FRAC_SCALE;
    const float s  = fmaf(fr, L.y, L.x);
    const float m  = (sqt < cut2) ? 1.0f : 0.0f;   // cut2=0 when !cm_j kills pair
    num = fmaf(m, s, num);
    den += m;
}

__global__ __launch_bounds__(NTHREADS) void lddt_tile_kernel(
    const float* __restrict__ pred, const float* __restrict__ tru,
    const int* __restrict__ is_dna, const int* __restrict__ is_rna,
    const int* __restrict__ cmask, const float2* __restrict__ gLUT,
    float* __restrict__ pnum, float* __restrict__ pden,
    int n, int T, int nslots)
{
    __shared__ __align__(16) float sPX[TS], sPY[TS], sPZ[TS];
    __shared__ __align__(16) float sTX[TS], sTY[TS], sTZ[TS];
    __shared__ __align__(16) float sCut[2 * TS];   // squared cutoffs [nt_i | other]
    __shared__ float2 sLUT[LUTN];
    __shared__ float wnum[4], wden[4];

    const int tid = threadIdx.x;

    // ---- decode block -> (bi, ti, tj) over upper-triangular tiles ----
    int slot = blockIdx.x;
    const int bi = slot / nslots;
    slot -= bi * nslots;
    const int W = 2 * T + 1;
    int ti = (int)(((float)W - fsqrt((float)(W * W - 8 * slot))) * 0.5f);
    while ((ti + 1) * (W - (ti + 1)) / 2 <= slot) ++ti;   // fixup fp rounding
    while (ti * (W - ti) / 2 > slot) --ti;
    const int tj = ti + (slot - ti * (W - ti) / 2);
    const bool diag = (ti == tj);
    const int i0 = ti * TS, j0 = tj * TS;
    const size_t base = (size_t)bi * n;

    // ---- copy precomputed LUT global->LDS (L2-broadcast, coalesced) ----
    #pragma unroll
    for (int e = tid; e < LUTN; e += NTHREADS) sLUT[e] = gLUT[e];

    // ---- stage j-tile (SoA) + per-j SQUARED cutoffs (cm_j & nt_j folded) ----
    if (tid < TS) {
        const int j = j0 + tid;
        const float* p = pred + (base + j) * 3;
        const float* q = tru  + (base + j) * 3;
        sPX[tid] = p[0]; sPY[tid] = p[1]; sPZ[tid] = p[2];
        sTX[tid] = q[0]; sTY[tid] = q[1]; sTZ[tid] = q[2];
        const bool ntj = (is_dna[base + j] != 0) || (is_rna[base + j] != 0);
        const bool cmj = (cmask[base + j] != 0);
        sCut[tid]      = cmj ? (ntj ? 900.0f : 225.0f) : 0.0f;
        sCut[TS + tid] = cmj ? 225.0f : 0.0f;
    }

    // ---- per-thread row data: 4 waves x 64 rows; wave w covers 16 j's ----
    const int il = tid & (TS - 1);
    const int i  = i0 + il;
    const float* p = pred + (base + i) * 3;
    const float* q = tru  + (base + i) * 3;
    const float pix = p[0], piy = p[1], piz = p[2];
    const float tix = q[0], tiy = q[1], tiz = q[2];
    const bool nti = (is_dna[base + i] != 0) || (is_rna[base + i] != 0);
    const float cmf = (cmask[base + i] != 0) ? 1.0f : 0.0f;
    __syncthreads();

    const float* cutsel = nti ? &sCut[0] : &sCut[TS];
    const char* lutB = (const char*)sLUT - IDX_BIAS;   // bias folded into base
    const int kbase = (tid >> 6) * JPT;   // wave-uniform -> LDS broadcast reads

    float num = 0.0f, den = 0.0f;
    const v2f px2 = {pix, pix}, py2 = {piy, piy}, pz2 = {piz, piz};
    const v2f tx2 = {tix, tix}, ty2 = {tiy, tiy}, tz2 = {tiz, tiz};

    #pragma unroll
    for (int qd = 0; qd < JPT / 4; ++qd) {
        const int jq = kbase + 4 * qd;
        const float4 PX = *(const float4*)&sPX[jq];
        const float4 PY = *(const float4*)&sPY[jq];
        const float4 PZ = *(const float4*)&sPZ[jq];
        const float4 TX = *(const float4*)&sTX[jq];
        const float4 TY = *(const float4*)&sTY[jq];
        const float4 TZ = *(const float4*)&sTZ[jq];
        const float4 CT = *(const float4*)&cutsel[jq];

        // duo A = (j, j+1), duo B = (j+2, j+3): packed f32 distance math
        v2f dx, dy, dz, sqpA, sqpB, sqtA, sqtB;

        dx = px2 - (v2f){PX.x, PX.y}; dy = py2 - (v2f){PY.x, PY.y}; dz = pz2 - (v2f){PZ.x, PZ.y};
        sqpA = dx * dx + dy * dy + dz * dz;
        dx = tx2 - (v2f){TX.x, TX.y}; dy = ty2 - (v2f){TY.x, TY.y}; dz = tz2 - (v2f){TZ.x, TZ.y};
        sqtA = dx * dx + dy * dy + dz * dz;

        dx = px2 - (v2f){PX.z, PX.w}; dy = py2 - (v2f){PY.z, PY.w}; dz = pz2 - (v2f){PZ.z, PZ.w};
        sqpB = dx * dx + dy * dy + dz * dz;
        dx = tx2 - (v2f){TX.z, TX.w}; dy = ty2 - (v2f){TY.z, TY.w}; dz = tz2 - (v2f){TZ.z, TZ.w};
        sqtB = dx * dx + dy * dy + dz * dz;

        pair_tail(sqpA.x, sqtA.x, CT.x, lutB, num, den);
        pair_tail(sqpA.y, sqtA.y, CT.y, lutB, num, den);
        pair_tail(sqpB.x, sqtB.x, CT.z, lutB, num, den);
        pair_tail(sqpB.y, sqtB.y, CT.w, lutB, num, den);
    }

    // fold row cm_i; remove self-pair contribution on diagonal tiles.
    // self pair: u=0 -> clamped to U_MIN -> LUT entry 0, frac 0 -> sLUT[0].x (exact)
    num *= cmf;
    den *= cmf;
    if (diag && tid < TS) {   // exactly once per row i
        num -= cmf * sLUT[0].x;
        den -= cmf;
    }

    // ---- wave (64) then block reduction ----
    #pragma unroll
    for (int off = 32; off > 0; off >>= 1) {
        num += __shfl_down(num, off, 64);
        den += __shfl_down(den, off, 64);
    }
    const int w = tid >> 6;
    if ((tid & 63) == 0) { wnum[w] = num; wden[w] = den; }
    __syncthreads();

    if (tid == 0) {
        const float tn = wnum[0] + wnum[1] + wnum[2] + wnum[3];
        const float td = wden[0] + wden[1] + wden[2] + wden[3];
        pnum[blockIdx.x] = diag ? tn : tn * 2.0f;   // off-diagonal tiles count twice
        pden[blockIdx.x] = diag ? td : td * 2.0f;
    }
}

__global__ __launch_bounds__(256) void lddt_final_kernel(
    const float* __restrict__ pnum, const float* __restrict__ pden,
    float* __restrict__ out, int nslots)
{
    __shared__ double sn0[4], sn1[4], sd0[4], sd1[4];
    double n0 = 0, n1 = 0, d0 = 0, d1 = 0;
    for (int s = threadIdx.x; s < 2 * nslots; s += 256) {
        if (s < nslots) { n0 += (double)pnum[s]; d0 += (double)pden[s]; }
        else            { n1 += (double)pnum[s]; d1 += (double)pden[s]; }
    }
    #pragma unroll
    for (int off = 32; off > 0; off >>= 1) {
        n0 += __shfl_down(n0, off, 64); d0 += __shfl_down(d0, off, 64);
        n1 += __shfl_down(n1, off, 64); d1 += __shfl_down(d1, off, 64);
    }
    const int w = threadIdx.x >> 6;
    if ((threadIdx.x & 63) == 0) { sn0[w] = n0; sn1[w] = n1; sd0[w] = d0; sd1[w] = d1; }
    __syncthreads();
    if (threadIdx.x == 0) {
        double N0 = sn0[0] + sn0[1] + sn0[2] + sn0[3];
        double N1 = sn1[0] + sn1[1] + sn1[2] + sn1[3];
        double D0 = sd0[0] + sd0[1] + sd0[2] + sd0[3];
        double D1 = sd1[0] + sd1[1] + sd1[2] + sd1[3];
        D0 = D0 > 1.0 ? D0 : 1.0;
        D1 = D1 > 1.0 ? D1 : 1.0;
        const double l0 = 0.25 * N0 / D0;   // 0.25 = mean over 4 thresholds
        const double l1 = 0.25 * N1 / D1;
        out[0] = (float)(1.0 - 0.5 * (l0 + l1));
    }
}

extern "C" void kernel_launch(void* const* d_in, const int* in_sizes, int n_in,
                              void* d_out, int out_size, void* d_ws, size_t ws_size,
                              hipStream_t stream) {
    const float* pred = (const float*)d_in[0];
    const float* tru  = (const float*)d_in[1];
    const int*   dna  = (const int*)d_in[2];
    const int*   rna  = (const int*)d_in[3];
    const int*   cm   = (const int*)d_in[4];
    float* out = (float*)d_out;

    const int B = 2;
    const int n = in_sizes[2] / B;        // is_dna has b*n elements
    const int T = n / TS;                 // 64 tiles per row
    const int nslots = T * (T + 1) / 2;   // 2080 per batch

    // ws layout: [LUT 768*float2 | pnum B*nslots | pden B*nslots]
    float2* gLUT = (float2*)d_ws;
    float* pnum = (float*)((char*)d_ws + (size_t)LUTN * sizeof(float2));
    float* pden = pnum + (size_t)B * nslots;

    const int grid = B * nslots;          // triangular launch: no dead blocks

    hipLaunchKernelGGL(lut_build_kernel, dim3((LUTN + 255) / 256), dim3(256), 0, stream,
                       gLUT);
    hipLaunchKernelGGL(lddt_tile_kernel, dim3(grid), dim3(NTHREADS), 0, stream,
                       pred, tru, dna, rna, cm, gLUT, pnum, pden, n, T, nslots);
    hipLaunchKernelGGL(lddt_final_kernel, dim3(1), dim3(256), 0, stream,
                       pnum, pden, out, nslots);
}

// Round 6
// 82.552 us; speedup vs baseline: 1.1064x; 1.0140x over previous
//
#include <hip/hip_runtime.h>
#include <math.h>

#define TS 64
#define NTHREADS 256
#define JPT 16                      // j's per thread (4 quads)

// ---- u = diff^2 LUT: float-bit indexed, nearest-midpoint, f32 entries.
// 24 octaves u in [2^-16, 2^8), 128 segments each -> 3072 entries (12 KB).
#define LUTN 3072
#define OCT_LO (-16)
#define U_MIN 1.52587890625e-5f     // 2^-16
#define U_MAX 255.999f              // just under 2^8
// entry index = (bits >> 16) - (111 << 7); as byte offset: (bits >> 14) - 56832
#define IDX_BYTE_BIAS 56832u

typedef float v2f __attribute__((ext_vector_type(2)));

__device__ __forceinline__ float fsqrt(float x) {
#if __has_builtin(__builtin_amdgcn_sqrtf)
    return __builtin_amdgcn_sqrtf(x);
#else
    return sqrtf(x);
#endif
}
__device__ __forceinline__ float fmed3(float x, float lo, float hi) {
#if __has_builtin(__builtin_amdgcn_fmed3f)
    return __builtin_amdgcn_fmed3f(x, lo, hi);
#else
    return fminf(fmaxf(x, lo), hi);
#endif
}

// f(d) = sum of 4 sigmoids sigma(thr - d); LUT-build kernel only (exact path)
__device__ __forceinline__ float sig4(float d) {
    const float e = expf(d);
    return 1.0f / (1.0f + e * 0.60653065971263342360f)   // exp(-0.5)
         + 1.0f / (1.0f + e * 0.36787944117144232160f)   // exp(-1)
         + 1.0f / (1.0f + e * 0.13533528323661269189f)   // exp(-2)
         + 1.0f / (1.0f + e * 0.01831563888873418029f);  // exp(-4)
}

// ---- one-time LUT build: f(sqrt(u_mid)) at each segment midpoint ----
__global__ __launch_bounds__(256) void lut_build_kernel(float* __restrict__ gLUT) {
    const int e = blockIdx.x * 256 + threadIdx.x;
    if (e < LUTN) {
        const int oct = e >> 7;                 // 0..23
        const int k   = e & 127;
        const float base2 = exp2f((float)(oct + OCT_LO));
        const float umid = base2 * (1.0f + ((float)k + 0.5f) * 0.0078125f);
        gLUT[e] = sig4(fsqrt(umid));
    }
}

__device__ __forceinline__ void pair_tail(float sqp, float sqt, float cut2,
                                          const char* __restrict__ lutB,
                                          float& num, float& den) {
    // diff^2 = sqt + sqp - 2*sqrt(sqt*sqp): ONE sqrt per pair
    const float r  = fsqrt(sqt * sqp);
    const float u0 = fmaf(-2.0f, r, sqt + sqp);
    const float u  = fmed3(u0, U_MIN, U_MAX);
    const unsigned int bits = __float_as_uint(u);
    const float s  = *(const float*)(lutB + ((bits >> 14) & ~3u));  // nearest-mid
    const float m  = (sqt < cut2) ? 1.0f : 0.0f;   // cut2=0 when !cm_j kills pair
    num = fmaf(m, s, num);
    den += m;
}

__global__ __launch_bounds__(NTHREADS) void lddt_tile_kernel(
    const float* __restrict__ pred, const float* __restrict__ tru,
    const int* __restrict__ is_dna, const int* __restrict__ is_rna,
    const int* __restrict__ cmask, const float* __restrict__ gLUT,
    float* __restrict__ pnum, float* __restrict__ pden,
    int n, int T, int nslots)
{
    __shared__ __align__(16) float sPX[TS], sPY[TS], sPZ[TS];
    __shared__ __align__(16) float sTX[TS], sTY[TS], sTZ[TS];
    __shared__ __align__(16) float sCut[2 * TS];   // squared cutoffs [nt_i | other]
    __shared__ __align__(16) float sLUT[LUTN];
    __shared__ float wnum[4], wden[4];

    const int tid = threadIdx.x;

    // ---- decode block -> (bi, ti, tj) over upper-triangular tiles ----
    int slot = blockIdx.x;
    const int bi = slot / nslots;
    slot -= bi * nslots;
    const int W = 2 * T + 1;
    int ti = (int)(((float)W - fsqrt((float)(W * W - 8 * slot))) * 0.5f);
    while ((ti + 1) * (W - (ti + 1)) / 2 <= slot) ++ti;   // fixup fp rounding
    while (ti * (W - ti) / 2 > slot) --ti;
    const int tj = ti + (slot - ti * (W - ti) / 2);
    const bool diag = (ti == tj);
    const int i0 = ti * TS, j0 = tj * TS;
    const size_t base = (size_t)bi * n;

    // ---- copy precomputed LUT global->LDS (float4, coalesced, L2-broadcast) ----
    {
        const float4* gl4 = (const float4*)gLUT;
        float4* sl4 = (float4*)sLUT;
        #pragma unroll
        for (int e = tid; e < LUTN / 4; e += NTHREADS) sl4[e] = gl4[e];
    }

    // ---- stage j-tile (SoA) + per-j SQUARED cutoffs (cm_j & nt_j folded) ----
    if (tid < TS) {
        const int j = j0 + tid;
        const float* p = pred + (base + j) * 3;
        const float* q = tru  + (base + j) * 3;
        sPX[tid] = p[0]; sPY[tid] = p[1]; sPZ[tid] = p[2];
        sTX[tid] = q[0]; sTY[tid] = q[1]; sTZ[tid] = q[2];
        const bool ntj = (is_dna[base + j] != 0) || (is_rna[base + j] != 0);
        const bool cmj = (cmask[base + j] != 0);
        sCut[tid]      = cmj ? (ntj ? 900.0f : 225.0f) : 0.0f;
        sCut[TS + tid] = cmj ? 225.0f : 0.0f;
    }

    // ---- per-thread row data: 4 waves x 64 rows; wave w covers 16 j's ----
    const int il = tid & (TS - 1);
    const int i  = i0 + il;
    const float* p = pred + (base + i) * 3;
    const float* q = tru  + (base + i) * 3;
    const float pix = p[0], piy = p[1], piz = p[2];
    const float tix = q[0], tiy = q[1], tiz = q[2];
    const bool nti = (is_dna[base + i] != 0) || (is_rna[base + i] != 0);
    const float cmf = (cmask[base + i] != 0) ? 1.0f : 0.0f;
    __syncthreads();

    const float* cutsel = nti ? &sCut[0] : &sCut[TS];
    const char* lutB = (const char*)sLUT - IDX_BYTE_BIAS;   // bias folded into base
    const int kbase = (tid >> 6) * JPT;   // wave-uniform -> LDS broadcast reads

    float num = 0.0f, den = 0.0f;
    const v2f px2 = {pix, pix}, py2 = {piy, piy}, pz2 = {piz, piz};
    const v2f tx2 = {tix, tix}, ty2 = {tiy, tiy}, tz2 = {tiz, tiz};

    #pragma unroll
    for (int qd = 0; qd < JPT / 4; ++qd) {
        const int jq = kbase + 4 * qd;
        const float4 PX = *(const float4*)&sPX[jq];
        const float4 PY = *(const float4*)&sPY[jq];
        const float4 PZ = *(const float4*)&sPZ[jq];
        const float4 TX = *(const float4*)&sTX[jq];
        const float4 TY = *(const float4*)&sTY[jq];
        const float4 TZ = *(const float4*)&sTZ[jq];
        const float4 CT = *(const float4*)&cutsel[jq];

        // duo A = (j, j+1), duo B = (j+2, j+3): packed f32 distance math
        v2f dx, dy, dz, sqpA, sqpB, sqtA, sqtB;

        dx = px2 - (v2f){PX.x, PX.y}; dy = py2 - (v2f){PY.x, PY.y}; dz = pz2 - (v2f){PZ.x, PZ.y};
        sqpA = dx * dx + dy * dy + dz * dz;
        dx = tx2 - (v2f){TX.x, TX.y}; dy = ty2 - (v2f){TY.x, TY.y}; dz = tz2 - (v2f){TZ.x, TZ.y};
        sqtA = dx * dx + dy * dy + dz * dz;

        dx = px2 - (v2f){PX.z, PX.w}; dy = py2 - (v2f){PY.z, PY.w}; dz = pz2 - (v2f){PZ.z, PZ.w};
        sqpB = dx * dx + dy * dy + dz * dz;
        dx = tx2 - (v2f){TX.z, TX.w}; dy = ty2 - (v2f){TY.z, TY.w}; dz = tz2 - (v2f){TZ.z, TZ.w};
        sqtB = dx * dx + dy * dy + dz * dz;

        pair_tail(sqpA.x, sqtA.x, CT.x, lutB, num, den);
        pair_tail(sqpA.y, sqtA.y, CT.y, lutB, num, den);
        pair_tail(sqpB.x, sqtB.x, CT.z, lutB, num, den);
        pair_tail(sqpB.y, sqtB.y, CT.w, lutB, num, den);
    }

    // fold row cm_i; remove self-pair contribution on diagonal tiles.
    // self pair: u=0 -> clamped to U_MIN -> LUT entry 0 -> sLUT[0] (bit-exact)
    num *= cmf;
    den *= cmf;
    if (diag && tid < TS) {   // exactly once per row i
        num -= cmf * sLUT[0];
        den -= cmf;
    }

    // ---- wave (64) then block reduction ----
    #pragma unroll
    for (int off = 32; off > 0; off >>= 1) {
        num += __shfl_down(num, off, 64);
        den += __shfl_down(den, off, 64);
    }
    const int w = tid >> 6;
    if ((tid & 63) == 0) { wnum[w] = num; wden[w] = den; }
    __syncthreads();

    if (tid == 0) {
        const float tn = wnum[0] + wnum[1] + wnum[2] + wnum[3];
        const float td = wden[0] + wden[1] + wden[2] + wden[3];
        pnum[blockIdx.x] = diag ? tn : tn * 2.0f;   // off-diagonal tiles count twice
        pden[blockIdx.x] = diag ? td : td * 2.0f;
    }
}

__global__ __launch_bounds__(256) void lddt_final_kernel(
    const float* __restrict__ pnum, const float* __restrict__ pden,
    float* __restrict__ out, int nslots)
{
    __shared__ double sn0[4], sn1[4], sd0[4], sd1[4];
    double n0 = 0, n1 = 0, d0 = 0, d1 = 0;
    for (int s = threadIdx.x; s < 2 * nslots; s += 256) {
        if (s < nslots) { n0 += (double)pnum[s]; d0 += (double)pden[s]; }
        else            { n1 += (double)pnum[s]; d1 += (double)pden[s]; }
    }
    #pragma unroll
    for (int off = 32; off > 0; off >>= 1) {
        n0 += __shfl_down(n0, off, 64); d0 += __shfl_down(d0, off, 64);
        n1 += __shfl_down(n1, off, 64); d1 += __shfl_down(d1, off, 64);
    }
    const int w = threadIdx.x >> 6;
    if ((threadIdx.x & 63) == 0) { sn0[w] = n0; sn1[w] = n1; sd0[w] = d0; sd1[w] = d1; }
    __syncthreads();
    if (threadIdx.x == 0) {
        double N0 = sn0[0] + sn0[1] + sn0[2] + sn0[3];
        double N1 = sn1[0] + sn1[1] + sn1[2] + sn1[3];
        double D0 = sd0[0] + sd0[1] + sd0[2] + sd0[3];
        double D1 = sd1[0] + sd1[1] + sd1[2] + sd1[3];
        D0 = D0 > 1.0 ? D0 : 1.0;
        D1 = D1 > 1.0 ? D1 : 1.0;
        const double l0 = 0.25 * N0 / D0;   // 0.25 = mean over 4 thresholds
        const double l1 = 0.25 * N1 / D1;
        out[0] = (float)(1.0 - 0.5 * (l0 + l1));
    }
}

extern "C" void kernel_launch(void* const* d_in, const int* in_sizes, int n_in,
                              void* d_out, int out_size, void* d_ws, size_t ws_size,
                              hipStream_t stream) {
    const float* pred = (const float*)d_in[0];
    const float* tru  = (const float*)d_in[1];
    const int*   dna  = (const int*)d_in[2];
    const int*   rna  = (const int*)d_in[3];
    const int*   cm   = (const int*)d_in[4];
    float* out = (float*)d_out;

    const int B = 2;
    const int n = in_sizes[2] / B;        // is_dna has b*n elements
    const int T = n / TS;                 // 64 tiles per row
    const int nslots = T * (T + 1) / 2;   // 2080 per batch

    // ws layout: [LUT 3072*f32 | pnum B*nslots | pden B*nslots]
    float* gLUT = (float*)d_ws;
    float* pnum = (float*)((char*)d_ws + (size_t)LUTN * sizeof(float));
    float* pden = pnum + (size_t)B * nslots;

    const int grid = B * nslots;          // triangular launch: no dead blocks

    hipLaunchKernelGGL(lut_build_kernel, dim3((LUTN + 255) / 256), dim3(256), 0, stream,
                       gLUT);
    hipLaunchKernelGGL(lddt_tile_kernel, dim3(grid), dim3(NTHREADS), 0, stream,
                       pred, tru, dna, rna, cm, gLUT, pnum, pden, n, T, nslots);
    hipLaunchKernelGGL(lddt_final_kernel, dim3(1), dim3(256), 0, stream,
                       pnum, pden, out, nslots);
}